// Round 6
// baseline (770.344 us; speedup 1.0000x reference)
//
#include <hip/hip_runtime.h>

#define SIDE 96
#define NN 9216            // SIDE*SIDE
#define BATCH 32
#define KC 64              // k-chunk staged in LDS
#define CPT 4              // columns per thread (one dwordx4 W load)
#define HB 16              // batches per lane (half-wave split)
#define CBLK 512           // cols per block = 4 waves * 32 * CPT
#define NCB (NN / CBLK)    // 18
#define SPLIT 72           // split-K slices
#define SLICE (NN / SPLIT) // 128 = 2 KC-chunks
#define PSTRIDE ((size_t)NN * BATCH)   // bf16 elems per partial slice

typedef __attribute__((ext_vector_type(8))) _Float16 half8;
typedef __attribute__((ext_vector_type(2))) _Float16 half2v;

__device__ __forceinline__ float clamp01(float v) {
    return fminf(fmaxf(v, 0.0f), 1.0f);
}

__device__ __forceinline__ unsigned int packbf2(float a, float b) {
    unsigned int ua = __float_as_uint(a);
    unsigned int ub = __float_as_uint(b);
    ua = (ua + 0x7fffu + ((ua >> 16) & 1u)) >> 16;   // RNE to bf16
    ub = (ub + 0x7fffu + ((ub >> 16) & 1u)) >> 16;
    return ua | (ub << 16);
}

__device__ __forceinline__ float bf2f(unsigned short u) {
    return __uint_as_float(((unsigned int)u) << 16);
}

// xt[j*32 + b] = (f16) x[b*NN + j]
__global__ __launch_bounds__(256) void k_transpose(const float* __restrict__ x,
                                                   _Float16* __restrict__ xt) {
    int idx = blockIdx.x * 256 + threadIdx.x;
    int j = idx >> 5;
    int b = idx & 31;
    xt[idx] = (_Float16)x[(size_t)b * NN + j];
}

// Partial GEMM: part[s][j][b] (bf16) = sum_{k in slice s} at[k][b] * W[k][j]
// Half-wave batch split: lane&31 picks 4 consecutive cols, lane>>5 picks the
// batch half -> acc is 64 regs. Activations are f16 in LDS (2 ds_read_b128
// per k-step per lane, uniform per half -> conflict-free), consumed via
// v_fma_mix_f32. LDS double-buffered with register prefetch; W stream
// software-pipelined 8 k-steps ahead across chunk boundaries.
__global__ __launch_bounds__(256, 2) void k_gemm_part(
    const float* __restrict__ W,        // [NN][NN] row-major (k-major)
    const _Float16* __restrict__ at,    // [NN][BATCH] f16
    unsigned int* __restrict__ part)    // [SPLIT][NN][BATCH/2] bf16x2
{
    __shared__ __align__(16) _Float16 sa[2][KC * BATCH];  // 2 x 4 KB

    const int tid  = threadIdx.x;
    const int wave = tid >> 6;
    const int lane = tid & 63;
    const int hl   = lane & 31;
    const int half = lane >> 5;
    const int b0   = half * HB;
    const int cb = blockIdx.x % NCB;
    const int s  = blockIdx.x / NCB;
    const int j0 = cb * CBLK + wave * 128 + hl * CPT;
    const size_t k0 = (size_t)s * SLICE;

    const float* Wp = W + k0 * NN + j0;
    // slice activations: SLICE*32 f16 = 8 KB = 512 float4; chunk = 256 float4
    const float4* ap = (const float4*)(at + k0 * BATCH);

    // stage chunk 0; issue chunk 1 load into registers (latency hides under
    // chunk-0 compute)
    float4 v0 = ap[tid];
    ((float4*)sa[0])[tid] = v0;
    float4 v1 = ap[256 + tid];

    float acc[CPT][HB];
#pragma unroll
    for (int c = 0; c < CPT; ++c)
#pragma unroll
        for (int b = 0; b < HB; ++b) acc[c][b] = 0.0f;

    // prime W pipeline (first 8 k-steps)
    float4 wcur[8], wnxt[8];
#pragma unroll
    for (int g = 0; g < 8; ++g)
        wcur[g] = *(const float4*)(Wp + (size_t)g * NN);

    __syncthreads();   // sa[0] visible

    for (int c = 0; c < 2; ++c) {
        const _Float16* sc = sa[c];
#pragma unroll
        for (int ug = 0; ug < KC; ug += 8) {
            const int nu = c * KC + ug + 8;      // next group's global u
            if (nu < SLICE) {
#pragma unroll
                for (int g = 0; g < 8; ++g)
                    wnxt[g] = *(const float4*)(Wp + (size_t)(nu + g) * NN);
            }
#pragma unroll
            for (int g = 0; g < 8; ++g) {
                const float4 wv = wcur[g];
                const half8 a0 = *(const half8*)(sc + (ug + g) * BATCH + b0);
                const half8 a1 = *(const half8*)(sc + (ug + g) * BATCH + b0 + 8);
#pragma unroll
                for (int e = 0; e < 8; ++e) {
                    const float ax = (float)a0[e];
                    acc[0][e] = fmaf(ax, wv.x, acc[0][e]);
                    acc[1][e] = fmaf(ax, wv.y, acc[1][e]);
                    acc[2][e] = fmaf(ax, wv.z, acc[2][e]);
                    acc[3][e] = fmaf(ax, wv.w, acc[3][e]);
                }
#pragma unroll
                for (int e = 0; e < 8; ++e) {
                    const float ay = (float)a1[e];
                    acc[0][8+e] = fmaf(ay, wv.x, acc[0][8+e]);
                    acc[1][8+e] = fmaf(ay, wv.y, acc[1][8+e]);
                    acc[2][8+e] = fmaf(ay, wv.z, acc[2][8+e]);
                    acc[3][8+e] = fmaf(ay, wv.w, acc[3][8+e]);
                }
            }
#pragma unroll
            for (int g = 0; g < 8; ++g) wcur[g] = wnxt[g];
        }
        if (c == 0) {
            ((float4*)sa[1])[tid] = v1;   // v1 arrived during chunk-0 compute
            __syncthreads();
        }
    }

    // store bf16 partials: per col, this lane's 16 batch values = 2 uint4
#pragma unroll
    for (int c = 0; c < CPT; ++c) {
        unsigned int* pp = part + ((size_t)s * NN + (size_t)(j0 + c)) * (BATCH / 2)
                         + half * (HB / 2);
        uint4 v0p, v1p;
        v0p.x = packbf2(acc[c][ 0], acc[c][ 1]);
        v0p.y = packbf2(acc[c][ 2], acc[c][ 3]);
        v0p.z = packbf2(acc[c][ 4], acc[c][ 5]);
        v0p.w = packbf2(acc[c][ 6], acc[c][ 7]);
        v1p.x = packbf2(acc[c][ 8], acc[c][ 9]);
        v1p.y = packbf2(acc[c][10], acc[c][11]);
        v1p.z = packbf2(acc[c][12], acc[c][13]);
        v1p.w = packbf2(acc[c][14], acc[c][15]);
        *(uint4*)pp       = v0p;
        *(uint4*)(pp + 4) = v1p;
    }
}

// afft[pair] = (f16) clamp01( sum_s part[s][pair] )
__global__ __launch_bounds__(256) void k_reduce_aff(const unsigned int* __restrict__ part,
                                                    _Float16* __restrict__ aff_t) {
    int t = blockIdx.x * 256 + threadIdx.x;     // over NN*BATCH/2
    float v0 = 0.0f, v1 = 0.0f;
    for (int s = 0; s < SPLIT; ++s) {
        unsigned int u = part[(size_t)s * (PSTRIDE / 2) + t];
        v0 += bf2f((unsigned short)(u & 0xffffu));
        v1 += bf2f((unsigned short)(u >> 16));
    }
    half2v o;
    o.x = (_Float16)clamp01(v0);
    o.y = (_Float16)clamp01(v1);
    ((half2v*)aff_t)[t] = o;
}

// Fused epilogue: reduce inhibitory bf16 partials, sparse excitatory gather
// (13 taps of the radius-2 circular mask), combine.
__global__ __launch_bounds__(256) void k_combine(
    const unsigned short* __restrict__ part,  // [SPLIT][NN][BATCH] bf16
    const _Float16* __restrict__ aff_t,       // [NN][BATCH] f16, clamped
    const float* __restrict__ We,             // [NN][NN]
    float* __restrict__ out)                  // [BATCH][NN]
{
    int idx = blockIdx.x * 256 + threadIdx.x;
    int j = idx >> 5;
    int b = idx & 31;

    float inh = 0.0f;
    for (int s = 0; s < SPLIT; ++s)
        inh += bf2f(part[(size_t)s * PSTRIDE + idx]);
    inh = clamp01(inh);

    int mx = j / SIDE;
    int my = j - mx * SIDE;

    const int dxs[13] = {-2,-1,-1,-1, 0, 0, 0, 0, 0, 1, 1, 1, 2};
    const int dys[13] = { 0,-1, 0, 1,-2,-1, 0, 1, 2,-1, 0, 1, 0};

    float exc = 0.0f;
#pragma unroll
    for (int t = 0; t < 13; ++t) {
        int x = mx + dxs[t];
        int y = my + dys[t];
        if ((unsigned)x < SIDE && (unsigned)y < SIDE) {
            int i = x * SIDE + y;
            float w = We[(size_t)i * NN + j];
            exc = fmaf((float)aff_t[(size_t)i * BATCH + b], w, exc);
        }
    }
    exc = clamp01(exc);

    float a = (float)aff_t[idx];
    out[(size_t)b * NN + j] = clamp01(a + 0.2f * exc - 0.4f * inh);
}

extern "C" void kernel_launch(void* const* d_in, const int* in_sizes, int n_in,
                              void* d_out, int out_size, void* d_ws, size_t ws_size,
                              hipStream_t stream) {
    const float* x  = (const float*)d_in[0];  // [32][9216]
    const float* Wr = (const float*)d_in[1];  // [9216][9216]
    const float* We = (const float*)d_in[2];  // [9216][9216] sparse (radius 2)
    const float* Wi = (const float*)d_in[3];  // [9216][9216]
    float* out = (float*)d_out;               // [32][9216]

    _Float16* xt   = (_Float16*)d_ws;                   // NN*32 f16
    _Float16* afft = xt + (size_t)NN * BATCH;           // NN*32 f16
    unsigned int* part = (unsigned int*)(afft + (size_t)NN * BATCH);
    // part: SPLIT * NN * 32 bf16 = 42.5 MB, reused by both GEMMs

    dim3 blk(256);
    dim3 grid_eb(NN * BATCH / 256);        // 1152
    dim3 grid_rd(NN * BATCH / 2 / 256);    // 576
    dim3 grid_gm(NCB * SPLIT);             // 1296

    k_transpose <<<grid_eb, blk, 0, stream>>>(x, xt);
    k_gemm_part <<<grid_gm, blk, 0, stream>>>(Wr, xt, part);
    k_reduce_aff<<<grid_rd, blk, 0, stream>>>(part, afft);
    k_gemm_part <<<grid_gm, blk, 0, stream>>>(Wi, afft, part);
    k_combine   <<<grid_eb, blk, 0, stream>>>((const unsigned short*)part, afft, We, out);
}

// Round 7
// 235.782 us; speedup vs baseline: 3.2672x; 3.2672x over previous
//
#include <hip/hip_runtime.h>

#define SIDE 96
#define NN 9216            // SIDE*SIDE
#define BATCH 32
#define KC 128             // whole k-slice staged in LDS once
#define CPT 8              // columns per thread (two dwordx4 W loads)
#define HB 8               // batches per lane (quarter-wave split)
#define CBLK 512           // cols per block = 4 waves * 16 * CPT
#define NCB (NN / CBLK)    // 18
#define SPLIT 72           // split-K slices
#define SLICE (NN / SPLIT) // 128 = KC
#define PSTRIDE ((size_t)NN * BATCH)   // bf16 elems per partial slice

__device__ __forceinline__ float clamp01(float v) {
    return fminf(fmaxf(v, 0.0f), 1.0f);
}

__device__ __forceinline__ unsigned int packbf2(float a, float b) {
    unsigned int ua = __float_as_uint(a);
    unsigned int ub = __float_as_uint(b);
    ua = (ua + 0x7fffu + ((ua >> 16) & 1u)) >> 16;   // RNE to bf16
    ub = (ub + 0x7fffu + ((ub >> 16) & 1u)) >> 16;
    return ua | (ub << 16);
}

__device__ __forceinline__ float bf2f(unsigned short u) {
    return __uint_as_float(((unsigned int)u) << 16);
}

// xt[j*32 + b] = x[b*NN + j]
__global__ __launch_bounds__(256) void k_transpose(const float* __restrict__ x,
                                                   float* __restrict__ xt) {
    int idx = blockIdx.x * 256 + threadIdx.x;
    int j = idx >> 5;
    int b = idx & 31;
    xt[idx] = x[(size_t)b * NN + j];
}

// Partial GEMM: part[s][j][b] (bf16) = sum_{k in slice s} at[k][b] * W[k][j]
// Quarter-wave batch split: lane&15 picks 8 consecutive cols (2 dwordx4 W
// loads per k), lane>>4 picks a batch quarter -> acc is 64 regs. The whole
// 128-row k-slice is staged in LDS once (16 KB, no mid-loop barriers).
// Activation ds_read_b128 are 16-lane same-address broadcasts (conflict-free).
// W stream software-pipelined 4 k-steps ahead.
__global__ __launch_bounds__(256, 2) void k_gemm_part(
    const float* __restrict__ W,      // [NN][NN] row-major (k-major)
    const float* __restrict__ at,     // [NN][BATCH]
    unsigned int* __restrict__ part)  // [SPLIT][NN][BATCH/2] bf16x2
{
    __shared__ __align__(16) float sa[KC * BATCH];   // 16 KB

    const int tid  = threadIdx.x;
    const int wave = tid >> 6;
    const int lane = tid & 63;
    const int hl   = lane & 15;
    const int grp  = lane >> 4;
    const int b0   = grp * HB;
    const int cb = blockIdx.x % NCB;
    const int s  = blockIdx.x / NCB;
    const int j0 = cb * CBLK + wave * 128 + hl * CPT;
    const size_t k0 = (size_t)s * SLICE;

    const float* Wp = W + k0 * NN + j0;
    const float4* ap = (const float4*)(at + k0 * BATCH);

    // stage the whole slice: SLICE*BATCH = 4096 floats = 1024 float4
    {
        float4* d = (float4*)sa;
        d[tid]       = ap[tid];
        d[tid + 256] = ap[tid + 256];
        d[tid + 512] = ap[tid + 512];
        d[tid + 768] = ap[tid + 768];
    }

    float acc[CPT][HB];
#pragma unroll
    for (int c = 0; c < CPT; ++c)
#pragma unroll
        for (int b = 0; b < HB; ++b) acc[c][b] = 0.0f;

    // prime W pipeline (4 k-steps, 2 dwordx4 each)
    float4 wcur[4][2], wnxt[4][2];
#pragma unroll
    for (int g = 0; g < 4; ++g) {
        wcur[g][0] = *(const float4*)(Wp + (size_t)g * NN);
        wcur[g][1] = *(const float4*)(Wp + (size_t)g * NN + 4);
    }

    __syncthreads();   // sa visible

#pragma unroll 4
    for (int ug = 0; ug < KC; ug += 4) {
        if (ug + 4 < KC) {
#pragma unroll
            for (int g = 0; g < 4; ++g) {
                wnxt[g][0] = *(const float4*)(Wp + (size_t)(ug + 4 + g) * NN);
                wnxt[g][1] = *(const float4*)(Wp + (size_t)(ug + 4 + g) * NN + 4);
            }
        }
#pragma unroll
        for (int g = 0; g < 4; ++g) {
            const int u = ug + g;
            const float4 a0 = *(const float4*)(sa + u * BATCH + b0);
            const float4 a1 = *(const float4*)(sa + u * BATCH + b0 + 4);
            const float av[HB] = {a0.x, a0.y, a0.z, a0.w, a1.x, a1.y, a1.z, a1.w};
            const float4 w0 = wcur[g][0];
            const float4 w1 = wcur[g][1];
            const float wv[CPT] = {w0.x, w0.y, w0.z, w0.w, w1.x, w1.y, w1.z, w1.w};
#pragma unroll
            for (int c = 0; c < CPT; ++c)
#pragma unroll
                for (int b = 0; b < HB; ++b)
                    acc[c][b] = fmaf(av[b], wv[c], acc[c][b]);
        }
#pragma unroll
        for (int g = 0; g < 4; ++g) {
            wcur[g][0] = wnxt[g][0];
            wcur[g][1] = wnxt[g][1];
        }
    }

    // store bf16 partials: per col, this lane's 8 batch values = 1 uint4
#pragma unroll
    for (int c = 0; c < CPT; ++c) {
        unsigned int* pp = part + ((size_t)s * NN + (size_t)(j0 + c)) * (BATCH / 2)
                         + grp * (HB / 2);
        uint4 v;
        v.x = packbf2(acc[c][0], acc[c][1]);
        v.y = packbf2(acc[c][2], acc[c][3]);
        v.z = packbf2(acc[c][4], acc[c][5]);
        v.w = packbf2(acc[c][6], acc[c][7]);
        *(uint4*)pp = v;
    }
}

// afft[pair] = clamp01( sum_s part[s][pair] ), one uint (2 bf16) per thread
__global__ __launch_bounds__(256) void k_reduce_aff(const unsigned int* __restrict__ part,
                                                    float* __restrict__ aff_t) {
    int t = blockIdx.x * 256 + threadIdx.x;     // over NN*BATCH/2
    float v0 = 0.0f, v1 = 0.0f;
    for (int s = 0; s < SPLIT; ++s) {
        unsigned int u = part[(size_t)s * (PSTRIDE / 2) + t];
        v0 += bf2f((unsigned short)(u & 0xffffu));
        v1 += bf2f((unsigned short)(u >> 16));
    }
    ((float2*)aff_t)[t] = make_float2(clamp01(v0), clamp01(v1));
}

// Fused epilogue: reduce inhibitory bf16 partials, sparse excitatory gather
// (13 taps of the radius-2 circular mask), combine.
__global__ __launch_bounds__(256) void k_combine(
    const unsigned short* __restrict__ part,  // [SPLIT][NN][BATCH] bf16
    const float* __restrict__ aff_t,          // [NN][BATCH], clamped
    const float* __restrict__ We,             // [NN][NN]
    float* __restrict__ out)                  // [BATCH][NN]
{
    int idx = blockIdx.x * 256 + threadIdx.x;
    int j = idx >> 5;
    int b = idx & 31;

    float inh = 0.0f;
    for (int s = 0; s < SPLIT; ++s)
        inh += bf2f(part[(size_t)s * PSTRIDE + idx]);
    inh = clamp01(inh);

    int mx = j / SIDE;
    int my = j - mx * SIDE;

    const int dxs[13] = {-2,-1,-1,-1, 0, 0, 0, 0, 0, 1, 1, 1, 2};
    const int dys[13] = { 0,-1, 0, 1,-2,-1, 0, 1, 2,-1, 0, 1, 0};

    float exc = 0.0f;
#pragma unroll
    for (int t = 0; t < 13; ++t) {
        int x = mx + dxs[t];
        int y = my + dys[t];
        if ((unsigned)x < SIDE && (unsigned)y < SIDE) {
            int i = x * SIDE + y;
            float w = We[(size_t)i * NN + j];
            exc = fmaf(aff_t[(size_t)i * BATCH + b], w, exc);
        }
    }
    exc = clamp01(exc);

    float a = aff_t[idx];
    out[(size_t)b * NN + j] = clamp01(a + 0.2f * exc - 0.4f * inh);
}

extern "C" void kernel_launch(void* const* d_in, const int* in_sizes, int n_in,
                              void* d_out, int out_size, void* d_ws, size_t ws_size,
                              hipStream_t stream) {
    const float* x  = (const float*)d_in[0];  // [32][9216]
    const float* Wr = (const float*)d_in[1];  // [9216][9216]
    const float* We = (const float*)d_in[2];  // [9216][9216] sparse (radius 2)
    const float* Wi = (const float*)d_in[3];  // [9216][9216]
    float* out = (float*)d_out;               // [32][9216]

    float* xt   = (float*)d_ws;                         // NN*32 fp32
    float* afft = xt + (size_t)NN * BATCH;              // NN*32 fp32
    unsigned int* part = (unsigned int*)(afft + (size_t)NN * BATCH);
    // part: SPLIT * NN * 32 bf16 = 42.5 MB, reused by both GEMMs

    dim3 blk(256);
    dim3 grid_eb(NN * BATCH / 256);        // 1152
    dim3 grid_rd(NN * BATCH / 2 / 256);    // 576
    dim3 grid_gm(NCB * SPLIT);             // 1296

    k_transpose <<<grid_eb, blk, 0, stream>>>(x, xt);
    k_gemm_part <<<grid_gm, blk, 0, stream>>>(Wr, xt, part);
    k_reduce_aff<<<grid_rd, blk, 0, stream>>>(part, afft);
    k_gemm_part <<<grid_gm, blk, 0, stream>>>(Wi, afft, part);
    k_combine   <<<grid_eb, blk, 0, stream>>>((const unsigned short*)part, afft, We, out);
}

// Round 8
// 229.615 us; speedup vs baseline: 3.3549x; 1.0269x over previous
//
#include <hip/hip_runtime.h>

#define SIDE 96
#define NN 9216            // SIDE*SIDE
#define BATCH 32
#define KC 128             // whole k-slice staged in LDS once
#define CPT 8              // columns per thread (two dwordx4 W loads)
#define HB 8               // batches per lane (quarter-wave split)
#define CBLK 512           // cols per block = 4 waves * 16 * CPT
#define NCB (NN / CBLK)    // 18
#define SPLIT 72           // split-K slices
#define SLICE (NN / SPLIT) // 128 = KC
#define PSTRIDE ((size_t)NN * BATCH)   // bf16 elems per partial slice

__device__ __forceinline__ float clamp01(float v) {
    return fminf(fmaxf(v, 0.0f), 1.0f);
}

__device__ __forceinline__ unsigned int packbf2(float a, float b) {
    unsigned int ua = __float_as_uint(a);
    unsigned int ub = __float_as_uint(b);
    ua = (ua + 0x7fffu + ((ua >> 16) & 1u)) >> 16;   // RNE to bf16
    ub = (ub + 0x7fffu + ((ub >> 16) & 1u)) >> 16;
    return ua | (ub << 16);
}

__device__ __forceinline__ float bf2f(unsigned short u) {
    return __uint_as_float(((unsigned int)u) << 16);
}

// xt[j*32 + b] = x[b*NN + j]
__global__ __launch_bounds__(256) void k_transpose(const float* __restrict__ x,
                                                   float* __restrict__ xt) {
    int idx = blockIdx.x * 256 + threadIdx.x;
    int j = idx >> 5;
    int b = idx & 31;
    xt[idx] = x[(size_t)b * NN + j];
}

#define FMA_BLOCK(w0, w1, a0, a1)                                   \
    {                                                               \
        const float av[HB] = {a0.x, a0.y, a0.z, a0.w,               \
                              a1.x, a1.y, a1.z, a1.w};              \
        const float wv[CPT] = {w0.x, w0.y, w0.z, w0.w,              \
                               w1.x, w1.y, w1.z, w1.w};             \
        _Pragma("unroll")                                           \
        for (int c = 0; c < CPT; ++c)                               \
            _Pragma("unroll")                                       \
            for (int b = 0; b < HB; ++b)                            \
                acc[c][b] = fmaf(av[b], wv[c], acc[c][b]);          \
    }

// Partial GEMM: part[s][j][b] (bf16) = sum_{k in slice s} at[k][b] * W[k][j]
// Quarter-wave batch split: lane&15 picks 8 consecutive cols (2 dwordx4 W
// loads per k), lane>>4 picks a batch quarter -> acc is 64 regs. Whole
// 128-row k-slice staged in LDS once (16 KB, no mid-loop barriers); LDS
// reads are 16-lane same-address broadcasts (conflict-free). W stream uses
// a 4-deep ROLLING register pipeline (load u+4 into the slot consumed at u)
// -> 32 W regs, no copy movs. launch_bounds(256,3) targets 3 waves/SIMD.
__global__ __launch_bounds__(256, 3) void k_gemm_part(
    const float* __restrict__ W,      // [NN][NN] row-major (k-major)
    const float* __restrict__ at,     // [NN][BATCH]
    unsigned int* __restrict__ part)  // [SPLIT][NN][BATCH/2] bf16x2
{
    __shared__ __align__(16) float sa[KC * BATCH];   // 16 KB

    const int tid  = threadIdx.x;
    const int wave = tid >> 6;
    const int lane = tid & 63;
    const int hl   = lane & 15;
    const int grp  = lane >> 4;
    const int b0   = grp * HB;
    const int cb = blockIdx.x % NCB;
    const int s  = blockIdx.x / NCB;
    const int j0 = cb * CBLK + wave * 128 + hl * CPT;
    const size_t k0 = (size_t)s * SLICE;

    const float* Wp = W + k0 * NN + j0;
    const float4* ap = (const float4*)(at + k0 * BATCH);

    // stage the whole slice: SLICE*BATCH = 4096 floats = 1024 float4
    {
        float4* d = (float4*)sa;
        d[tid]       = ap[tid];
        d[tid + 256] = ap[tid + 256];
        d[tid + 512] = ap[tid + 512];
        d[tid + 768] = ap[tid + 768];
    }

    float acc[CPT][HB];
#pragma unroll
    for (int c = 0; c < CPT; ++c)
#pragma unroll
        for (int b = 0; b < HB; ++b) acc[c][b] = 0.0f;

    // prime rolling W pipeline (4 k-steps, 2 dwordx4 each)
    float4 wbuf[4][2];
#pragma unroll
    for (int g = 0; g < 4; ++g) {
        wbuf[g][0] = *(const float4*)(Wp + (size_t)g * NN);
        wbuf[g][1] = *(const float4*)(Wp + (size_t)g * NN + 4);
    }

    __syncthreads();   // sa visible

#pragma unroll 1
    for (int ug = 0; ug + 4 < KC; ug += 4) {
#pragma unroll
        for (int g = 0; g < 4; ++g) {
            const int u = ug + g;
            const float4 w0 = wbuf[g][0];
            const float4 w1 = wbuf[g][1];
            // refill the consumed slot with k-step u+4 (issues before the
            // FMA block retires; ~512 wave-cycles of cover)
            wbuf[g][0] = *(const float4*)(Wp + (size_t)(u + 4) * NN);
            wbuf[g][1] = *(const float4*)(Wp + (size_t)(u + 4) * NN + 4);
            const float4 a0 = *(const float4*)(sa + u * BATCH + b0);
            const float4 a1 = *(const float4*)(sa + u * BATCH + b0 + 4);
            FMA_BLOCK(w0, w1, a0, a1)
        }
    }
    // tail: last 4 k-steps, no refill
    {
        const int ug = KC - 4;
#pragma unroll
        for (int g = 0; g < 4; ++g) {
            const int u = ug + g;
            const float4 w0 = wbuf[g][0];
            const float4 w1 = wbuf[g][1];
            const float4 a0 = *(const float4*)(sa + u * BATCH + b0);
            const float4 a1 = *(const float4*)(sa + u * BATCH + b0 + 4);
            FMA_BLOCK(w0, w1, a0, a1)
        }
    }

    // store bf16 partials: per col, this lane's 8 batch values = 1 uint4
#pragma unroll
    for (int c = 0; c < CPT; ++c) {
        unsigned int* pp = part + ((size_t)s * NN + (size_t)(j0 + c)) * (BATCH / 2)
                         + grp * (HB / 2);
        uint4 v;
        v.x = packbf2(acc[c][0], acc[c][1]);
        v.y = packbf2(acc[c][2], acc[c][3]);
        v.z = packbf2(acc[c][4], acc[c][5]);
        v.w = packbf2(acc[c][6], acc[c][7]);
        *(uint4*)pp = v;
    }
}

// afft[pair] = clamp01( sum_s part[s][pair] ), one uint (2 bf16) per thread
__global__ __launch_bounds__(256) void k_reduce_aff(const unsigned int* __restrict__ part,
                                                    float* __restrict__ aff_t) {
    int t = blockIdx.x * 256 + threadIdx.x;     // over NN*BATCH/2
    float v0 = 0.0f, v1 = 0.0f;
    for (int s = 0; s < SPLIT; ++s) {
        unsigned int u = part[(size_t)s * (PSTRIDE / 2) + t];
        v0 += bf2f((unsigned short)(u & 0xffffu));
        v1 += bf2f((unsigned short)(u >> 16));
    }
    ((float2*)aff_t)[t] = make_float2(clamp01(v0), clamp01(v1));
}

// Fused epilogue: reduce inhibitory bf16 partials, sparse excitatory gather
// (13 taps of the radius-2 circular mask), combine.
__global__ __launch_bounds__(256) void k_combine(
    const unsigned short* __restrict__ part,  // [SPLIT][NN][BATCH] bf16
    const float* __restrict__ aff_t,          // [NN][BATCH], clamped
    const float* __restrict__ We,             // [NN][NN]
    float* __restrict__ out)                  // [BATCH][NN]
{
    int idx = blockIdx.x * 256 + threadIdx.x;
    int j = idx >> 5;
    int b = idx & 31;

    float inh = 0.0f;
    for (int s = 0; s < SPLIT; ++s)
        inh += bf2f(part[(size_t)s * PSTRIDE + idx]);
    inh = clamp01(inh);

    int mx = j / SIDE;
    int my = j - mx * SIDE;

    const int dxs[13] = {-2,-1,-1,-1, 0, 0, 0, 0, 0, 1, 1, 1, 2};
    const int dys[13] = { 0,-1, 0, 1,-2,-1, 0, 1, 2,-1, 0, 1, 0};

    float exc = 0.0f;
#pragma unroll
    for (int t = 0; t < 13; ++t) {
        int x = mx + dxs[t];
        int y = my + dys[t];
        if ((unsigned)x < SIDE && (unsigned)y < SIDE) {
            int i = x * SIDE + y;
            float w = We[(size_t)i * NN + j];
            exc = fmaf(aff_t[(size_t)i * BATCH + b], w, exc);
        }
    }
    exc = clamp01(exc);

    float a = aff_t[idx];
    out[(size_t)b * NN + j] = clamp01(a + 0.2f * exc - 0.4f * inh);
}

extern "C" void kernel_launch(void* const* d_in, const int* in_sizes, int n_in,
                              void* d_out, int out_size, void* d_ws, size_t ws_size,
                              hipStream_t stream) {
    const float* x  = (const float*)d_in[0];  // [32][9216]
    const float* Wr = (const float*)d_in[1];  // [9216][9216]
    const float* We = (const float*)d_in[2];  // [9216][9216] sparse (radius 2)
    const float* Wi = (const float*)d_in[3];  // [9216][9216]
    float* out = (float*)d_out;               // [32][9216]

    float* xt   = (float*)d_ws;                         // NN*32 fp32
    float* afft = xt + (size_t)NN * BATCH;              // NN*32 fp32
    unsigned int* part = (unsigned int*)(afft + (size_t)NN * BATCH);
    // part: SPLIT * NN * 32 bf16 = 42.5 MB, reused by both GEMMs

    dim3 blk(256);
    dim3 grid_eb(NN * BATCH / 256);        // 1152
    dim3 grid_rd(NN * BATCH / 2 / 256);    // 576
    dim3 grid_gm(NCB * SPLIT);             // 1296

    k_transpose <<<grid_eb, blk, 0, stream>>>(x, xt);
    k_gemm_part <<<grid_gm, blk, 0, stream>>>(Wr, xt, part);
    k_reduce_aff<<<grid_rd, blk, 0, stream>>>(part, afft);
    k_gemm_part <<<grid_gm, blk, 0, stream>>>(Wi, afft, part);
    k_combine   <<<grid_eb, blk, 0, stream>>>((const unsigned short*)part, afft, We, out);
}

// Round 9
// 175.452 us; speedup vs baseline: 4.3906x; 1.3087x over previous
//
#include <hip/hip_runtime.h>

#define SIDE 96
#define NN 9216            // SIDE*SIDE
#define BATCH 32
#define SPLIT 72           // split-K slices
#define SLICE (NN / SPLIT) // 128
#define NKT (SLICE / 16)   // 8 k-tiles (K=16 each) per slice
#define NJB (NN / 128)     // 72 j-blocks (128 cols per block, 32 per wave)
#define PSTRIDE ((size_t)NN * BATCH)   // bf16 elems per partial slice

typedef __attribute__((ext_vector_type(8)))  short  short8;
typedef __attribute__((ext_vector_type(16))) float  f32x16;
typedef __attribute__((ext_vector_type(4)))  unsigned int uintx4;

__device__ __forceinline__ float clamp01(float v) {
    return fminf(fmaxf(v, 0.0f), 1.0f);
}

__device__ __forceinline__ unsigned short f2bf(float f) {  // RNE fp32->bf16
    unsigned int u = __float_as_uint(f);
    return (unsigned short)((u + 0x7fffu + ((u >> 16) & 1u)) >> 16);
}

__device__ __forceinline__ unsigned int packbf2(float a, float b) {
    return (unsigned int)f2bf(a) | ((unsigned int)f2bf(b) << 16);
}

__device__ __forceinline__ float bf2f(unsigned short u) {
    return __uint_as_float(((unsigned int)u) << 16);
}

// atf[kt][l][i] = bf16(x[b][k]),  k = kt*16 + (l>>5)*8 + i,  b = l&31.
// This is exactly the MFMA B-fragment order: lane l, k-slot ((l>>5), i).
__global__ __launch_bounds__(256) void k_prep_x(const float* __restrict__ x,
                                                unsigned short* __restrict__ atf) {
    int o = blockIdx.x * 256 + threadIdx.x;   // over NN*BATCH
    int kt = o >> 9, r = o & 511, l = r >> 3, i = r & 7;
    int b = l & 31, g = l >> 5;
    int k = kt * 16 + g * 8 + i;
    atf[o] = f2bf(x[(size_t)b * NN + k]);
}

// Partial GEMM via MFMA: part[s][j][b] (bf16) = sum_{k in slice s} at[k][b]*W[k][j]
// Wave computes one 32j x 32b tile. A-frag = W^T (8 strided dword loads,
// 2x128B segments per instr, RNE-packed to bf16). B-frag = pre-formatted
// activations (one dwordx4 per k-tile, L2-resident). Both operands use the
// same (g,i)->k slot formula, so the hardware k-permutation cancels.
// C/D mapping (verified): col=lane&31, row=(reg&3)+8*(reg>>2)+4*(lane>>5).
__global__ __launch_bounds__(256, 4) void k_gemm_mfma(
    const float* __restrict__ W,             // [NN][NN] k-major
    const unsigned short* __restrict__ atf,  // fragment-ordered activations
    unsigned short* __restrict__ part)       // [SPLIT][NN][BATCH] bf16
{
    const int tid  = threadIdx.x;
    const int wave = tid >> 6;
    const int lane = tid & 63;
    const int jl   = lane & 31;
    const int g    = lane >> 5;
    const int jb = blockIdx.x % NJB;
    const int s  = blockIdx.x / NJB;
    const int j  = jb * 128 + wave * 32 + jl;
    const size_t k0 = (size_t)s * SLICE;

    const float* wp = W + (k0 + (size_t)g * 8) * NN + j;
    const uintx4* bp = (const uintx4*)atf + (k0 >> 4) * 64 + lane;

    f32x16 acc;
#pragma unroll
    for (int e = 0; e < 16; ++e) acc[e] = 0.0f;

    float  wb[2][8];
    uintx4 bb[2];
#pragma unroll
    for (int i = 0; i < 8; ++i) wb[0][i] = wp[(size_t)i * NN];
    bb[0] = bp[0];

#pragma unroll
    for (int kt = 0; kt < NKT; ++kt) {
        const int cur = kt & 1, nxt = cur ^ 1;
        if (kt + 1 < NKT) {   // prefetch next k-tile (compile-time branch)
#pragma unroll
            for (int i = 0; i < 8; ++i)
                wb[nxt][i] = wp[((size_t)(kt + 1) * 16 + i) * NN];
            bb[nxt] = bp[(kt + 1) * 64];
        }
        uintx4 ap;
        ap[0] = packbf2(wb[cur][0], wb[cur][1]);
        ap[1] = packbf2(wb[cur][2], wb[cur][3]);
        ap[2] = packbf2(wb[cur][4], wb[cur][5]);
        ap[3] = packbf2(wb[cur][6], wb[cur][7]);
        short8 af = __builtin_bit_cast(short8, ap);
        short8 bf = __builtin_bit_cast(short8, bb[cur]);
        acc = __builtin_amdgcn_mfma_f32_32x32x16_bf16(af, bf, acc, 0, 0, 0);
    }

    unsigned short* pp = part + ((size_t)s * NN + (size_t)jb * 128 + wave * 32) * BATCH + jl;
#pragma unroll
    for (int r2 = 0; r2 < 16; ++r2) {
        int row = (r2 & 3) + 8 * (r2 >> 2) + 4 * g;
        pp[(size_t)row * BATCH] = f2bf(acc[r2]);
    }
}

// afft[k][b] = clamp01( sum_s part[s][k][b] ) (fp32), and the same value
// re-emitted in MFMA fragment order (bf16) for the second GEMM.
__global__ __launch_bounds__(256) void k_reduce_aff(
    const unsigned int* __restrict__ part,
    float* __restrict__ afft,
    unsigned short* __restrict__ atf2)
{
    int t = blockIdx.x * 256 + threadIdx.x;   // over NN*BATCH/2
    float v0 = 0.0f, v1 = 0.0f;
    for (int s = 0; s < SPLIT; ++s) {
        unsigned int u = part[(size_t)s * (PSTRIDE / 2) + t];
        v0 += bf2f((unsigned short)(u & 0xffffu));
        v1 += bf2f((unsigned short)(u >> 16));
    }
    v0 = clamp01(v0);
    v1 = clamp01(v1);
    ((float2*)afft)[t] = make_float2(v0, v1);

    int k = t >> 4, b = (t & 15) * 2;
    int kt = k >> 4, g = (k >> 3) & 1, i = k & 7;
    int l = g * 32 + b;
    size_t o = (size_t)kt * 512 + (size_t)l * 8 + i;
    atf2[o]     = f2bf(v0);
    atf2[o + 8] = f2bf(v1);
}

// Fused epilogue: reduce inhibitory bf16 partials, sparse excitatory gather
// (13 taps of the radius-2 circular mask), combine.
__global__ __launch_bounds__(256) void k_combine(
    const unsigned short* __restrict__ part,  // [SPLIT][NN][BATCH] bf16
    const float* __restrict__ afft,           // [NN][BATCH], clamped
    const float* __restrict__ We,             // [NN][NN]
    float* __restrict__ out)                  // [BATCH][NN]
{
    int idx = blockIdx.x * 256 + threadIdx.x;
    int j = idx >> 5;
    int b = idx & 31;

    float inh = 0.0f;
    for (int s = 0; s < SPLIT; ++s)
        inh += bf2f(part[(size_t)s * PSTRIDE + idx]);
    inh = clamp01(inh);

    int mx = j / SIDE;
    int my = j - mx * SIDE;

    const int dxs[13] = {-2,-1,-1,-1, 0, 0, 0, 0, 0, 1, 1, 1, 2};
    const int dys[13] = { 0,-1, 0, 1,-2,-1, 0, 1, 2,-1, 0, 1, 0};

    float exc = 0.0f;
#pragma unroll
    for (int t = 0; t < 13; ++t) {
        int x = mx + dxs[t];
        int y = my + dys[t];
        if ((unsigned)x < SIDE && (unsigned)y < SIDE) {
            int i = x * SIDE + y;
            float w = We[(size_t)i * NN + j];
            exc = fmaf(afft[(size_t)i * BATCH + b], w, exc);
        }
    }
    exc = clamp01(exc);

    float a = afft[idx];
    out[(size_t)b * NN + j] = clamp01(a + 0.2f * exc - 0.4f * inh);
}

extern "C" void kernel_launch(void* const* d_in, const int* in_sizes, int n_in,
                              void* d_out, int out_size, void* d_ws, size_t ws_size,
                              hipStream_t stream) {
    const float* x  = (const float*)d_in[0];  // [32][9216]
    const float* Wr = (const float*)d_in[1];  // [9216][9216]
    const float* We = (const float*)d_in[2];  // [9216][9216] sparse (radius 2)
    const float* Wi = (const float*)d_in[3];  // [9216][9216]
    float* out = (float*)d_out;               // [32][9216]

    unsigned short* atf1 = (unsigned short*)d_ws;        // NN*32 bf16 (frag order)
    float* afft = (float*)(atf1 + (size_t)NN * BATCH);   // NN*32 fp32
    unsigned short* atf2 = (unsigned short*)(afft + (size_t)NN * BATCH);
    unsigned short* part = atf2 + (size_t)NN * BATCH;    // SPLIT*NN*32 bf16 = 42.5 MB

    dim3 blk(256);
    dim3 grid_eb(NN * BATCH / 256);        // 1152
    dim3 grid_rd(NN * BATCH / 2 / 256);    // 576
    dim3 grid_gm(NJB * SPLIT);             // 5184

    k_prep_x   <<<grid_eb, blk, 0, stream>>>(x, atf1);
    k_gemm_mfma<<<grid_gm, blk, 0, stream>>>(Wr, atf1, part);
    k_reduce_aff<<<grid_rd, blk, 0, stream>>>((const unsigned int*)part, afft, atf2);
    k_gemm_mfma<<<grid_gm, blk, 0, stream>>>(Wi, atf2, part);
    k_combine  <<<grid_eb, blk, 0, stream>>>(part, afft, We, out);
}

// Round 10
// 174.106 us; speedup vs baseline: 4.4246x; 1.0077x over previous
//
#include <hip/hip_runtime.h>

#define SIDE 96
#define NN 9216            // SIDE*SIDE
#define BATCH 32
#define SPLIT 72           // split-K slices
#define SLICE (NN / SPLIT) // 128
#define NKT (SLICE / 16)   // 8 k-tiles (K=16 each) per slice
#define NJB (NN / 128)     // 72 j-blocks (128 cols per block, 32 per wave)
#define PSTRIDE ((size_t)NN * BATCH)   // bf16 elems per partial slice

typedef __attribute__((ext_vector_type(8)))  short  short8;
typedef __attribute__((ext_vector_type(16))) float  f32x16;
typedef __attribute__((ext_vector_type(4)))  unsigned int uintx4;

__device__ __forceinline__ float clamp01(float v) {
    return fminf(fmaxf(v, 0.0f), 1.0f);
}

__device__ __forceinline__ unsigned short f2bf(float f) {  // RNE fp32->bf16
    unsigned int u = __float_as_uint(f);
    return (unsigned short)((u + 0x7fffu + ((u >> 16) & 1u)) >> 16);
}

__device__ __forceinline__ unsigned int packbf2(float a, float b) {
    return (unsigned int)f2bf(a) | ((unsigned int)f2bf(b) << 16);
}

__device__ __forceinline__ float bf2f(unsigned short u) {
    return __uint_as_float(((unsigned int)u) << 16);
}

// atf[kt][l][i] = bf16(x[b][k]),  k = kt*16 + (l>>5)*8 + i,  b = l&31.
// Exactly the MFMA B-fragment order: lane l, k-slot ((l>>5), i).
__global__ __launch_bounds__(256) void k_prep_x(const float* __restrict__ x,
                                                unsigned short* __restrict__ atf) {
    int o = blockIdx.x * 256 + threadIdx.x;   // over NN*BATCH
    int kt = o >> 9, r = o & 511, l = r >> 3, i = r & 7;
    int b = l & 31, g = l >> 5;
    int k = kt * 16 + g * 8 + i;
    atf[o] = f2bf(x[(size_t)b * NN + k]);
}

// Partial GEMM via MFMA: part[s][j][b] (bf16) = sum_{k in slice s} at[k][b]*W[k][j]
// Wave computes one 32j x 32b tile. A-frag = W^T (8 strided dword loads,
// RNE-packed to bf16). B-frag = pre-formatted activations (one dwordx4 per
// k-tile, L2-resident). Same (g,i)->k slot formula on both operands, so the
// hardware k-permutation cancels. C/D: col=lane&31, row=(r&3)+8*(r>>2)+4*g.
__global__ __launch_bounds__(256, 5) void k_gemm_mfma(
    const float* __restrict__ W,             // [NN][NN] k-major
    const unsigned short* __restrict__ atf,  // fragment-ordered activations
    unsigned short* __restrict__ part)       // [SPLIT][NN][BATCH] bf16
{
    const int tid  = threadIdx.x;
    const int wave = tid >> 6;
    const int lane = tid & 63;
    const int jl   = lane & 31;
    const int g    = lane >> 5;
    const int jb = blockIdx.x % NJB;
    const int s  = blockIdx.x / NJB;
    const int j  = jb * 128 + wave * 32 + jl;
    const size_t k0 = (size_t)s * SLICE;

    const float* wp = W + (k0 + (size_t)g * 8) * NN + j;
    const uintx4* bp = (const uintx4*)atf + (k0 >> 4) * 64 + lane;

    f32x16 acc;
#pragma unroll
    for (int e = 0; e < 16; ++e) acc[e] = 0.0f;

    float  wb[2][8];
    uintx4 bb[2];
#pragma unroll
    for (int i = 0; i < 8; ++i) wb[0][i] = wp[(size_t)i * NN];
    bb[0] = bp[0];

#pragma unroll
    for (int kt = 0; kt < NKT; ++kt) {
        const int cur = kt & 1, nxt = cur ^ 1;
        if (kt + 1 < NKT) {   // prefetch next k-tile (compile-time branch)
#pragma unroll
            for (int i = 0; i < 8; ++i)
                wb[nxt][i] = wp[((size_t)(kt + 1) * 16 + i) * NN];
            bb[nxt] = bp[(kt + 1) * 64];
        }
        uintx4 ap;
        ap[0] = packbf2(wb[cur][0], wb[cur][1]);
        ap[1] = packbf2(wb[cur][2], wb[cur][3]);
        ap[2] = packbf2(wb[cur][4], wb[cur][5]);
        ap[3] = packbf2(wb[cur][6], wb[cur][7]);
        short8 af = __builtin_bit_cast(short8, ap);
        short8 bf = __builtin_bit_cast(short8, bb[cur]);
        acc = __builtin_amdgcn_mfma_f32_32x32x16_bf16(af, bf, acc, 0, 0, 0);
    }

    unsigned short* pp = part + ((size_t)s * NN + (size_t)jb * 128 + wave * 32) * BATCH + jl;
#pragma unroll
    for (int r2 = 0; r2 < 16; ++r2) {
        int row = (r2 & 3) + 8 * (r2 >> 2) + 4 * g;
        pp[(size_t)row * BATCH] = f2bf(acc[r2]);
    }
}

// afft[k][b] = clamp01( sum_s part[s][k][b] ) (fp32), plus the same values
// re-emitted in MFMA B-fragment order (bf16) for the second GEMM.
// One thread handles 4 consecutive elements (same k, b0=4-aligned).
__global__ __launch_bounds__(256) void k_reduce_aff(
    const uint2* __restrict__ part,          // viewing bf16x4
    float* __restrict__ afft,
    unsigned short* __restrict__ atf2)
{
    int t = blockIdx.x * 256 + threadIdx.x;   // over NN*BATCH/4
    float v0 = 0.0f, v1 = 0.0f, v2 = 0.0f, v3 = 0.0f;
    for (int s = 0; s < SPLIT; ++s) {
        uint2 u = part[(size_t)s * (PSTRIDE / 4) + t];
        v0 += bf2f((unsigned short)(u.x & 0xffffu));
        v1 += bf2f((unsigned short)(u.x >> 16));
        v2 += bf2f((unsigned short)(u.y & 0xffffu));
        v3 += bf2f((unsigned short)(u.y >> 16));
    }
    v0 = clamp01(v0); v1 = clamp01(v1); v2 = clamp01(v2); v3 = clamp01(v3);
    float4 o = make_float4(v0, v1, v2, v3);
    ((float4*)afft)[t] = o;

    int k = t >> 3, b = (t & 7) * 4;
    int kt = k >> 4, g = (k >> 3) & 1, i = k & 7;
    size_t ob = (size_t)kt * 512 + (size_t)(g * 32 + b) * 8 + i;
    atf2[ob]      = f2bf(v0);
    atf2[ob + 8]  = f2bf(v1);
    atf2[ob + 16] = f2bf(v2);
    atf2[ob + 24] = f2bf(v3);
}

// Fused epilogue: reduce inhibitory bf16 partials (paired dword loads),
// sparse excitatory gather (13 taps of radius-2 circular mask), combine.
// One thread per (j, batch-pair).
__global__ __launch_bounds__(256) void k_combine(
    const unsigned int* __restrict__ part,    // [SPLIT][NN][BATCH] bf16, as pairs
    const float* __restrict__ afft,           // [NN][BATCH], clamped
    const float* __restrict__ We,             // [NN][NN]
    float* __restrict__ out)                  // [BATCH][NN]
{
    int t = blockIdx.x * 256 + threadIdx.x;   // over NN*BATCH/2
    int j  = t >> 4;
    int bp = t & 15;                          // batch pair: b = 2bp, 2bp+1

    float i0 = 0.0f, i1 = 0.0f;
    for (int s = 0; s < SPLIT; ++s) {
        unsigned int u = part[(size_t)s * (PSTRIDE / 2) + t];
        i0 += bf2f((unsigned short)(u & 0xffffu));
        i1 += bf2f((unsigned short)(u >> 16));
    }
    i0 = clamp01(i0);
    i1 = clamp01(i1);

    int mx = j / SIDE;
    int my = j - mx * SIDE;

    const int dxs[13] = {-2,-1,-1,-1, 0, 0, 0, 0, 0, 1, 1, 1, 2};
    const int dys[13] = { 0,-1, 0, 1,-2,-1, 0, 1, 2,-1, 0, 1, 0};

    float e0 = 0.0f, e1 = 0.0f;
#pragma unroll
    for (int tp = 0; tp < 13; ++tp) {
        int xx = mx + dxs[tp];
        int yy = my + dys[tp];
        if ((unsigned)xx < SIDE && (unsigned)yy < SIDE) {
            int i = xx * SIDE + yy;
            float w = We[(size_t)i * NN + j];
            float2 av = ((const float2*)afft)[(size_t)i * 16 + bp];
            e0 = fmaf(av.x, w, e0);
            e1 = fmaf(av.y, w, e1);
        }
    }
    e0 = clamp01(e0);
    e1 = clamp01(e1);

    float2 a = ((const float2*)afft)[t];
    out[(size_t)(2 * bp)     * NN + j] = clamp01(a.x + 0.2f * e0 - 0.4f * i0);
    out[(size_t)(2 * bp + 1) * NN + j] = clamp01(a.y + 0.2f * e1 - 0.4f * i1);
}

extern "C" void kernel_launch(void* const* d_in, const int* in_sizes, int n_in,
                              void* d_out, int out_size, void* d_ws, size_t ws_size,
                              hipStream_t stream) {
    const float* x  = (const float*)d_in[0];  // [32][9216]
    const float* Wr = (const float*)d_in[1];  // [9216][9216]
    const float* We = (const float*)d_in[2];  // [9216][9216] sparse (radius 2)
    const float* Wi = (const float*)d_in[3];  // [9216][9216]
    float* out = (float*)d_out;               // [32][9216]

    unsigned short* atf1 = (unsigned short*)d_ws;        // NN*32 bf16 (frag order)
    float* afft = (float*)(atf1 + (size_t)NN * BATCH);   // NN*32 fp32
    unsigned short* atf2 = (unsigned short*)(afft + (size_t)NN * BATCH);
    unsigned short* part = atf2 + (size_t)NN * BATCH;    // SPLIT*NN*32 bf16 = 42.5 MB

    dim3 blk(256);
    dim3 grid_eb(NN * BATCH / 256);        // 1152
    dim3 grid_r4(NN * BATCH / 4 / 256);    // 288
    dim3 grid_r2(NN * BATCH / 2 / 256);    // 576
    dim3 grid_gm(NJB * SPLIT);             // 5184

    k_prep_x    <<<grid_eb, blk, 0, stream>>>(x, atf1);
    k_gemm_mfma <<<grid_gm, blk, 0, stream>>>(Wr, atf1, part);
    k_reduce_aff<<<grid_r4, blk, 0, stream>>>((const uint2*)part, afft, atf2);
    k_gemm_mfma <<<grid_gm, blk, 0, stream>>>(Wi, atf2, part);
    k_combine   <<<grid_r2, blk, 0, stream>>>((const unsigned int*)part, afft, We, out);
}

// Round 11
// 166.160 us; speedup vs baseline: 4.6362x; 1.0478x over previous
//
#include <hip/hip_runtime.h>

#define SIDE 96
#define NN 9216            // SIDE*SIDE
#define BATCH 32
#define SPLIT 48           // split-K slices (was 72: grid 3456 = 2.7 rounds
                           // at 5 blocks/CU -> ~90% slot util; partials -33%)
#define SLICE (NN / SPLIT) // 192
#define NKT (SLICE / 16)   // 12 k-tiles (K=16 each) per slice
#define NJB (NN / 128)     // 72 j-blocks (128 cols per block, 32 per wave)
#define PSTRIDE ((size_t)NN * BATCH)   // bf16 elems per partial slice

typedef __attribute__((ext_vector_type(8)))  short  short8;
typedef __attribute__((ext_vector_type(16))) float  f32x16;
typedef __attribute__((ext_vector_type(4)))  unsigned int uintx4;

__device__ __forceinline__ float clamp01(float v) {
    return fminf(fmaxf(v, 0.0f), 1.0f);
}

__device__ __forceinline__ unsigned short f2bf(float f) {  // RNE fp32->bf16
    unsigned int u = __float_as_uint(f);
    return (unsigned short)((u + 0x7fffu + ((u >> 16) & 1u)) >> 16);
}

__device__ __forceinline__ unsigned int packbf2(float a, float b) {
    return (unsigned int)f2bf(a) | ((unsigned int)f2bf(b) << 16);
}

__device__ __forceinline__ float bf2f(unsigned short u) {
    return __uint_as_float(((unsigned int)u) << 16);
}

// atf[kt][l][i] = bf16(x[b][k]),  k = kt*16 + (l>>5)*8 + i,  b = l&31.
// Exactly the MFMA B-fragment order: lane l, k-slot ((l>>5), i).
__global__ __launch_bounds__(256) void k_prep_x(const float* __restrict__ x,
                                                unsigned short* __restrict__ atf) {
    int o = blockIdx.x * 256 + threadIdx.x;   // over NN*BATCH
    int kt = o >> 9, r = o & 511, l = r >> 3, i = r & 7;
    int b = l & 31, g = l >> 5;
    int k = kt * 16 + g * 8 + i;
    atf[o] = f2bf(x[(size_t)b * NN + k]);
}

// Partial GEMM via MFMA: part[s][j][b] (bf16) = sum_{k in slice s} at[k][b]*W[k][j]
// Wave computes one 32j x 32b tile. A-frag = W^T (8 strided dword loads,
// RNE-packed to bf16). B-frag = pre-formatted activations (one dwordx4 per
// k-tile, L2-resident). Same (g,i)->k slot formula on both operands, so the
// hardware k-permutation cancels. C/D: col=lane&31, row=(r&3)+8*(r>>2)+4*g.
__global__ __launch_bounds__(256, 5) void k_gemm_mfma(
    const float* __restrict__ W,             // [NN][NN] k-major
    const unsigned short* __restrict__ atf,  // fragment-ordered activations
    unsigned short* __restrict__ part)       // [SPLIT][NN][BATCH] bf16
{
    const int tid  = threadIdx.x;
    const int wave = tid >> 6;
    const int lane = tid & 63;
    const int jl   = lane & 31;
    const int g    = lane >> 5;
    const int jb = blockIdx.x % NJB;
    const int s  = blockIdx.x / NJB;
    const int j  = jb * 128 + wave * 32 + jl;
    const size_t k0 = (size_t)s * SLICE;

    const float* wp = W + (k0 + (size_t)g * 8) * NN + j;
    const uintx4* bp = (const uintx4*)atf + (k0 >> 4) * 64 + lane;

    f32x16 acc;
#pragma unroll
    for (int e = 0; e < 16; ++e) acc[e] = 0.0f;

    float  wb[2][8];
    uintx4 bb[2];
#pragma unroll
    for (int i = 0; i < 8; ++i) wb[0][i] = wp[(size_t)i * NN];
    bb[0] = bp[0];

#pragma unroll
    for (int kt = 0; kt < NKT; ++kt) {
        const int cur = kt & 1, nxt = cur ^ 1;
        if (kt + 1 < NKT) {   // prefetch next k-tile (compile-time branch)
#pragma unroll
            for (int i = 0; i < 8; ++i)
                wb[nxt][i] = wp[((size_t)(kt + 1) * 16 + i) * NN];
            bb[nxt] = bp[(kt + 1) * 64];
        }
        uintx4 ap;
        ap[0] = packbf2(wb[cur][0], wb[cur][1]);
        ap[1] = packbf2(wb[cur][2], wb[cur][3]);
        ap[2] = packbf2(wb[cur][4], wb[cur][5]);
        ap[3] = packbf2(wb[cur][6], wb[cur][7]);
        short8 af = __builtin_bit_cast(short8, ap);
        short8 bf = __builtin_bit_cast(short8, bb[cur]);
        acc = __builtin_amdgcn_mfma_f32_32x32x16_bf16(af, bf, acc, 0, 0, 0);
    }

    unsigned short* pp = part + ((size_t)s * NN + (size_t)jb * 128 + wave * 32) * BATCH + jl;
#pragma unroll
    for (int r2 = 0; r2 < 16; ++r2) {
        int row = (r2 & 3) + 8 * (r2 >> 2) + 4 * g;
        pp[(size_t)row * BATCH] = f2bf(acc[r2]);
    }
}

// afft[k][b] = clamp01( sum_s part[s][k][b] ) (fp32), plus the same values
// re-emitted in MFMA B-fragment order (bf16) for the second GEMM.
// One thread handles 4 consecutive elements (same k, b0=4-aligned).
__global__ __launch_bounds__(256) void k_reduce_aff(
    const uint2* __restrict__ part,          // viewing bf16x4
    float* __restrict__ afft,
    unsigned short* __restrict__ atf2)
{
    int t = blockIdx.x * 256 + threadIdx.x;   // over NN*BATCH/4
    float v0 = 0.0f, v1 = 0.0f, v2 = 0.0f, v3 = 0.0f;
    for (int s = 0; s < SPLIT; ++s) {
        uint2 u = part[(size_t)s * (PSTRIDE / 4) + t];
        v0 += bf2f((unsigned short)(u.x & 0xffffu));
        v1 += bf2f((unsigned short)(u.x >> 16));
        v2 += bf2f((unsigned short)(u.y & 0xffffu));
        v3 += bf2f((unsigned short)(u.y >> 16));
    }
    v0 = clamp01(v0); v1 = clamp01(v1); v2 = clamp01(v2); v3 = clamp01(v3);
    float4 o = make_float4(v0, v1, v2, v3);
    ((float4*)afft)[t] = o;

    int k = t >> 3, b = (t & 7) * 4;
    int kt = k >> 4, g = (k >> 3) & 1, i = k & 7;
    size_t ob = (size_t)kt * 512 + (size_t)(g * 32 + b) * 8 + i;
    atf2[ob]      = f2bf(v0);
    atf2[ob + 8]  = f2bf(v1);
    atf2[ob + 16] = f2bf(v2);
    atf2[ob + 24] = f2bf(v3);
}

// Fused epilogue: reduce inhibitory bf16 partials (paired dword loads),
// sparse excitatory gather (13 taps of radius-2 circular mask), combine.
// One thread per (j, batch-pair).
__global__ __launch_bounds__(256) void k_combine(
    const unsigned int* __restrict__ part,    // [SPLIT][NN][BATCH] bf16, as pairs
    const float* __restrict__ afft,           // [NN][BATCH], clamped
    const float* __restrict__ We,             // [NN][NN]
    float* __restrict__ out)                  // [BATCH][NN]
{
    int t = blockIdx.x * 256 + threadIdx.x;   // over NN*BATCH/2
    int j  = t >> 4;
    int bp = t & 15;                          // batch pair: b = 2bp, 2bp+1

    float i0 = 0.0f, i1 = 0.0f;
    for (int s = 0; s < SPLIT; ++s) {
        unsigned int u = part[(size_t)s * (PSTRIDE / 2) + t];
        i0 += bf2f((unsigned short)(u & 0xffffu));
        i1 += bf2f((unsigned short)(u >> 16));
    }
    i0 = clamp01(i0);
    i1 = clamp01(i1);

    int mx = j / SIDE;
    int my = j - mx * SIDE;

    const int dxs[13] = {-2,-1,-1,-1, 0, 0, 0, 0, 0, 1, 1, 1, 2};
    const int dys[13] = { 0,-1, 0, 1,-2,-1, 0, 1, 2,-1, 0, 1, 0};

    float e0 = 0.0f, e1 = 0.0f;
#pragma unroll
    for (int tp = 0; tp < 13; ++tp) {
        int xx = mx + dxs[tp];
        int yy = my + dys[tp];
        if ((unsigned)xx < SIDE && (unsigned)yy < SIDE) {
            int i = xx * SIDE + yy;
            float w = We[(size_t)i * NN + j];
            float2 av = ((const float2*)afft)[(size_t)i * 16 + bp];
            e0 = fmaf(av.x, w, e0);
            e1 = fmaf(av.y, w, e1);
        }
    }
    e0 = clamp01(e0);
    e1 = clamp01(e1);

    float2 a = ((const float2*)afft)[t];
    out[(size_t)(2 * bp)     * NN + j] = clamp01(a.x + 0.2f * e0 - 0.4f * i0);
    out[(size_t)(2 * bp + 1) * NN + j] = clamp01(a.y + 0.2f * e1 - 0.4f * i1);
}

extern "C" void kernel_launch(void* const* d_in, const int* in_sizes, int n_in,
                              void* d_out, int out_size, void* d_ws, size_t ws_size,
                              hipStream_t stream) {
    const float* x  = (const float*)d_in[0];  // [32][9216]
    const float* Wr = (const float*)d_in[1];  // [9216][9216]
    const float* We = (const float*)d_in[2];  // [9216][9216] sparse (radius 2)
    const float* Wi = (const float*)d_in[3];  // [9216][9216]
    float* out = (float*)d_out;               // [32][9216]

    unsigned short* atf1 = (unsigned short*)d_ws;        // NN*32 bf16 (frag order)
    float* afft = (float*)(atf1 + (size_t)NN * BATCH);   // NN*32 fp32
    unsigned short* atf2 = (unsigned short*)(afft + (size_t)NN * BATCH);
    unsigned short* part = atf2 + (size_t)NN * BATCH;    // SPLIT*NN*32 bf16 = 28.3 MB

    dim3 blk(256);
    dim3 grid_eb(NN * BATCH / 256);        // 1152
    dim3 grid_r4(NN * BATCH / 4 / 256);    // 288
    dim3 grid_r2(NN * BATCH / 2 / 256);    // 576
    dim3 grid_gm(NJB * SPLIT);             // 3456

    k_prep_x    <<<grid_eb, blk, 0, stream>>>(x, atf1);
    k_gemm_mfma <<<grid_gm, blk, 0, stream>>>(Wr, atf1, part);
    k_reduce_aff<<<grid_r4, blk, 0, stream>>>((const uint2*)part, afft, atf2);
    k_gemm_mfma <<<grid_gm, blk, 0, stream>>>(Wi, atf2, part);
    k_combine   <<<grid_r2, blk, 0, stream>>>((const unsigned int*)part, afft, We, out);
}